// Round 2
// baseline (550.980 us; speedup 1.0000x reference)
//
#include <hip/hip_runtime.h>

#define NB 16384
#define ND 512
#define NH 128
#define NHH 256
#define NG 18

typedef short s8v __attribute__((ext_vector_type(8)));
typedef __bf16 bf8v __attribute__((ext_vector_type(8)));
typedef float f4v __attribute__((ext_vector_type(4)));
typedef unsigned int u4v __attribute__((ext_vector_type(4)));

static __device__ __forceinline__ unsigned short f2bf(float f) {
  unsigned int u = __builtin_bit_cast(unsigned int, f);
  u += 0x7FFFu + ((u >> 16) & 1u);
  return (unsigned short)(u >> 16);
}

static __device__ __forceinline__ f4v mfma16(s8v a, s8v b, f4v c) {
  return __builtin_amdgcn_mfma_f32_16x16x32_bf16(
      __builtin_bit_cast(bf8v, a), __builtin_bit_cast(bf8v, b), c, 0, 0, 0);
}

// ---- weight transpose+convert: out[g][c][r] = bf16(in[g][r][c]) ----
__global__ __launch_bounds__(256) void k_transpose(const float* __restrict__ in,
                                                   unsigned short* __restrict__ out,
                                                   int R, int C) {
  __shared__ float t[64][65];
  const int g = blockIdx.y;
  const int nCt = C >> 6;
  const int tr = blockIdx.x / nCt;
  const int tc = blockIdx.x - tr * nCt;
  const int lw = threadIdx.x >> 6;
  const int lc = threadIdx.x & 63;
  const float* ip = in + (size_t)g * R * C + (size_t)(tr << 6) * C + (tc << 6);
#pragma unroll
  for (int i = 0; i < 16; ++i) {
    int r = (i << 2) + lw;
    t[r][lc] = ip[(size_t)r * C + lc];
  }
  __syncthreads();
  unsigned short* op = out + (size_t)g * R * C + (size_t)(tc << 6) * R + (tr << 6);
#pragma unroll
  for (int i = 0; i < 16; ++i) {
    int r = (i << 2) + lw;
    op[(size_t)r * R + lc] = f2bf(t[lc][r]);
  }
}

// Wa [512][18] -> WaT [18][512] f32
__global__ __launch_bounds__(256) void k_wat(const float* __restrict__ wa,
                                             float* __restrict__ wat) {
  int tid = blockIdx.x * 256 + threadIdx.x;
  if (tid < NG * ND) {
    int g = tid >> 9, d = tid & (ND - 1);
    wat[tid] = wa[d * NG + g];
  }
}

// attention weights w[B,G] = softmax(X@Wa+ba)*gv, plus X -> bf16
__global__ __launch_bounds__(256) void k_attn(const float* __restrict__ X,
                                              const float* __restrict__ GV,
                                              const float* __restrict__ wat,
                                              const float* __restrict__ ba,
                                              float* __restrict__ w,
                                              unsigned short* __restrict__ xb) {
  __shared__ float wl[NG * ND];
  const int tid = threadIdx.x;
  for (int i = tid; i < NG * ND; i += 256) wl[i] = wat[i];
  __syncthreads();
  const int lane = tid & 63;
  const int row = (blockIdx.x << 2) + (tid >> 6);
  const float* xr = X + (size_t)row * ND + (lane << 3);
  float x[8];
  {
    float4 a = *(const float4*)xr;
    float4 b = *(const float4*)(xr + 4);
    x[0] = a.x; x[1] = a.y; x[2] = a.z; x[3] = a.w;
    x[4] = b.x; x[5] = b.y; x[6] = b.z; x[7] = b.w;
  }
  {
    u4v p;
#pragma unroll
    for (int j = 0; j < 4; ++j)
      p[j] = (unsigned)f2bf(x[2 * j]) | ((unsigned)f2bf(x[2 * j + 1]) << 16);
    *(u4v*)(xb + (size_t)row * ND + (lane << 3)) = p;
  }
  float lg[NG];
#pragma unroll
  for (int g = 0; g < NG; ++g) {
    const float* wr = wl + g * ND + (lane << 3);
    float s = 0.f;
#pragma unroll
    for (int j = 0; j < 8; ++j) s += x[j] * wr[j];
    lg[g] = s;
  }
#pragma unroll
  for (int off = 32; off > 0; off >>= 1) {
#pragma unroll
    for (int g = 0; g < NG; ++g) lg[g] += __shfl_xor(lg[g], off);
  }
  float m = -3.4e38f;
#pragma unroll
  for (int g = 0; g < NG; ++g) { lg[g] += ba[g]; m = fmaxf(m, lg[g]); }
  float s = 0.f;
#pragma unroll
  for (int g = 0; g < NG; ++g) { lg[g] = expf(lg[g] - m); s += lg[g]; }
  float inv = 1.f / s;
  if (lane < NG) {
    float gv = GV[(size_t)row * NG + lane];
    w[(size_t)row * NG + lane] = gv > 0.f ? lg[lane] * inv * gv : 0.f;
  }
}

// fused experts + aggregation. 1 block = 64 rows, 16 waves.
__global__ __launch_bounds__(1024) void k_main(
    const unsigned short* __restrict__ xb,    // [B][512] bf16
    const float* __restrict__ wbg,            // [B][18]
    const unsigned short* __restrict__ w1t,   // [18][256][512] bf16
    const unsigned short* __restrict__ w2t,   // [18][128][256]
    const unsigned short* __restrict__ w3t,   // [18][128][128]
    const unsigned short* __restrict__ waggt, // [512][640]
    const float* __restrict__ b1, const float* __restrict__ b2,
    const float* __restrict__ b3, const float* __restrict__ bagg,
    float* __restrict__ out) {
  __shared__ __align__(16) char smem[119808];
  char* const XT = smem;                 // [64][512] bf16, stride 1024B, swz
  char* const H1 = smem + 65536;         // [64][256] bf16, stride 512B, swz
  char* const H2 = smem + 98304;         // [64][128] bf16, stride 256B, swz
  float* const WL = (float*)(smem + 114688); // [64][20]

  const int tid = threadIdx.x;
  const int row0 = blockIdx.x << 6;

#pragma unroll
  for (int i = 0; i < 4; ++i) {
    int idx = (i << 10) + tid;
    int r = idx >> 6, c16 = idx & 63;
    u4v v = *(const u4v*)(xb + ((size_t)(row0 + r) << 9) + (c16 << 3));
    int byte = (r << 10) + (c16 << 4);
    *(u4v*)(XT + (byte ^ ((r & 7) << 4))) = v;
  }
  for (int i = tid; i < 64 * NG; i += 1024) {
    int r = i / NG, g = i - r * NG;
    WL[r * 20 + g] = wbg[(size_t)(row0 + r) * NG + g];
  }
  __syncthreads();

  const int wid = tid >> 6, lane = tid & 63;
  const int lr = lane & 15, lk = lane >> 4;
  // GEMM1: wave grid 2(M) x 8(N)
  const int m1 = (wid >> 3) << 5;
  const int c1 = (wid & 7) << 5;
  // GEMM2/3: wave grid 4(M) x 4(N)
  const int m2 = (wid >> 2) << 4;
  const int c2 = (wid & 3) << 5;
  // GEMM4: wave grid 2(M) x 8(N)
  const int m4 = (wid >> 3) << 5;
  const int c4 = (wid & 7) << 6;

  f4v racc[2];
  racc[0] = (f4v){0.f, 0.f, 0.f, 0.f};
  racc[1] = (f4v){0.f, 0.f, 0.f, 0.f};

  for (int g = 0; g < NG; ++g) {
    // ---------- GEMM1: h1 = relu(X @ W1[g] + b1[g])  [64,256] ----------
    const unsigned short* const w1g = w1t + (size_t)g * (NHH * ND);
    const float bv1[2] = {b1[g * NHH + c1 + lr], b1[g * NHH + c1 + 16 + lr]};
    const unsigned short* const bp10 = w1g + ((size_t)(c1 + lr) << 9) + (lk << 3);
    const unsigned short* const bp11 = w1g + ((size_t)(c1 + 16 + lr) << 9) + (lk << 3);
    f4v acc1[2][2];
#pragma unroll
    for (int mi = 0; mi < 2; ++mi)
#pragma unroll
      for (int ni = 0; ni < 2; ++ni) acc1[mi][ni] = (f4v){0.f, 0.f, 0.f, 0.f};
#pragma unroll 4
    for (int ks = 0; ks < 16; ++ks) {
      const int cb = (ks << 6) + (lk << 4);
      s8v a0, a1, b0, b1v;
      {
        int row = m1 + lr;
        a0 = *(const s8v*)(XT + (((row << 10) + cb) ^ ((row & 7) << 4)));
        row = m1 + 16 + lr;
        a1 = *(const s8v*)(XT + (((row << 10) + cb) ^ ((row & 7) << 4)));
      }
      b0 = *(const s8v*)(bp10 + (ks << 5));
      b1v = *(const s8v*)(bp11 + (ks << 5));
      acc1[0][0] = mfma16(a0, b0, acc1[0][0]);
      acc1[0][1] = mfma16(a0, b1v, acc1[0][1]);
      acc1[1][0] = mfma16(a1, b0, acc1[1][0]);
      acc1[1][1] = mfma16(a1, b1v, acc1[1][1]);
    }
#pragma unroll
    for (int mi = 0; mi < 2; ++mi)
#pragma unroll
      for (int ni = 0; ni < 2; ++ni)
#pragma unroll
        for (int r = 0; r < 4; ++r) {
          const int row = m1 + (mi << 4) + (lk << 2) + r;
          const int col = c1 + (ni << 4) + lr;
          float v = fmaxf(acc1[mi][ni][r] + bv1[ni], 0.f);
          const int byte = (row << 9) + (col << 1);
          *(unsigned short*)(H1 + (byte ^ ((row & 7) << 4))) = f2bf(v);
        }
    __syncthreads();

    // ---------- GEMM2: h2 = relu(h1 @ W2[g] + b2[g])  [64,128] ----------
    const unsigned short* const w2g = w2t + (size_t)g * (NH * NHH);
    const float bv2[2] = {b2[g * NH + c2 + lr], b2[g * NH + c2 + 16 + lr]};
    const unsigned short* const bp20 = w2g + ((size_t)(c2 + lr) << 8) + (lk << 3);
    const unsigned short* const bp21 = w2g + ((size_t)(c2 + 16 + lr) << 8) + (lk << 3);
    f4v acc2[2];
    acc2[0] = (f4v){0.f, 0.f, 0.f, 0.f};
    acc2[1] = (f4v){0.f, 0.f, 0.f, 0.f};
#pragma unroll
    for (int ks = 0; ks < 8; ++ks) {
      const int cb = (ks << 6) + (lk << 4);
      const int row = m2 + lr;
      s8v a = *(const s8v*)(H1 + (((row << 9) + cb) ^ ((row & 7) << 4)));
      s8v b0 = *(const s8v*)(bp20 + (ks << 5));
      s8v b1v = *(const s8v*)(bp21 + (ks << 5));
      acc2[0] = mfma16(a, b0, acc2[0]);
      acc2[1] = mfma16(a, b1v, acc2[1]);
    }
#pragma unroll
    for (int ni = 0; ni < 2; ++ni)
#pragma unroll
      for (int r = 0; r < 4; ++r) {
        const int row = m2 + (lk << 2) + r;
        const int col = c2 + (ni << 4) + lr;
        float v = fmaxf(acc2[ni][r] + bv2[ni], 0.f);
        const int byte = (row << 8) + (col << 1);
        *(unsigned short*)(H2 + (byte ^ ((row & 7) << 4))) = f2bf(v);
      }
    __syncthreads();

    // ---------- GEMM3: h3 = h2 @ W3[g] + b3[g]; racc += w*h3 ----------
    const unsigned short* const w3g = w3t + (size_t)g * (NH * NH);
    const float bv3[2] = {b3[g * NH + c2 + lr], b3[g * NH + c2 + 16 + lr]};
    const unsigned short* const bp30 = w3g + ((size_t)(c2 + lr) << 7) + (lk << 3);
    const unsigned short* const bp31 = w3g + ((size_t)(c2 + 16 + lr) << 7) + (lk << 3);
    f4v acc3[2];
    acc3[0] = (f4v){0.f, 0.f, 0.f, 0.f};
    acc3[1] = (f4v){0.f, 0.f, 0.f, 0.f};
#pragma unroll
    for (int ks = 0; ks < 4; ++ks) {
      const int cb = (ks << 6) + (lk << 4);
      const int row = m2 + lr;
      s8v a = *(const s8v*)(H2 + (((row << 8) + cb) ^ ((row & 7) << 4)));
      s8v b0 = *(const s8v*)(bp30 + (ks << 5));
      s8v b1v = *(const s8v*)(bp31 + (ks << 5));
      acc3[0] = mfma16(a, b0, acc3[0]);
      acc3[1] = mfma16(a, b1v, acc3[1]);
    }
#pragma unroll
    for (int ni = 0; ni < 2; ++ni)
#pragma unroll
      for (int r = 0; r < 4; ++r) {
        const int row = m2 + (lk << 2) + r;
        const float wv = WL[row * 20 + g];
        racc[ni][r] += wv * (acc3[ni][r] + bv3[ni]);
      }
  }

  __syncthreads();  // all GEMM3 H2 reads done before overwrite with ref
#pragma unroll
  for (int ni = 0; ni < 2; ++ni)
#pragma unroll
    for (int r = 0; r < 4; ++r) {
      const int row = m2 + (lk << 2) + r;
      const int col = c2 + (ni << 4) + lr;
      const int byte = (row << 8) + (col << 1);
      *(unsigned short*)(H2 + (byte ^ ((row & 7) << 4))) = f2bf(racc[ni][r]);
    }
  __syncthreads();

  // ---------- GEMM4: out = relu([X | ref] @ Wagg + bagg)  [64,512] ----------
  float bv4[4];
#pragma unroll
  for (int ni = 0; ni < 4; ++ni) bv4[ni] = bagg[c4 + (ni << 4) + lr];
  const unsigned short* bp4[4];
#pragma unroll
  for (int ni = 0; ni < 4; ++ni)
    bp4[ni] = waggt + (size_t)(c4 + (ni << 4) + lr) * 640 + (lk << 3);
  f4v acc4[2][4];
#pragma unroll
  for (int mi = 0; mi < 2; ++mi)
#pragma unroll
    for (int ni = 0; ni < 4; ++ni) acc4[mi][ni] = (f4v){0.f, 0.f, 0.f, 0.f};
#pragma unroll 4
  for (int ks = 0; ks < 16; ++ks) {
    const int cb = (ks << 6) + (lk << 4);
    s8v a0, a1, bb[4];
    {
      int row = m4 + lr;
      a0 = *(const s8v*)(XT + (((row << 10) + cb) ^ ((row & 7) << 4)));
      row = m4 + 16 + lr;
      a1 = *(const s8v*)(XT + (((row << 10) + cb) ^ ((row & 7) << 4)));
    }
#pragma unroll
    for (int ni = 0; ni < 4; ++ni) bb[ni] = *(const s8v*)(bp4[ni] + (ks << 5));
#pragma unroll
    for (int ni = 0; ni < 4; ++ni) {
      acc4[0][ni] = mfma16(a0, bb[ni], acc4[0][ni]);
      acc4[1][ni] = mfma16(a1, bb[ni], acc4[1][ni]);
    }
  }
#pragma unroll
  for (int kh = 0; kh < 4; ++kh) {
    const int cb = (kh << 6) + (lk << 4);
    s8v a0, a1, bb[4];
    {
      int row = m4 + lr;
      a0 = *(const s8v*)(H2 + (((row << 8) + cb) ^ ((row & 7) << 4)));
      row = m4 + 16 + lr;
      a1 = *(const s8v*)(H2 + (((row << 8) + cb) ^ ((row & 7) << 4)));
    }
#pragma unroll
    for (int ni = 0; ni < 4; ++ni)
      bb[ni] = *(const s8v*)(bp4[ni] + ((16 + kh) << 5));
#pragma unroll
    for (int ni = 0; ni < 4; ++ni) {
      acc4[0][ni] = mfma16(a0, bb[ni], acc4[0][ni]);
      acc4[1][ni] = mfma16(a1, bb[ni], acc4[1][ni]);
    }
  }
#pragma unroll
  for (int mi = 0; mi < 2; ++mi)
#pragma unroll
    for (int ni = 0; ni < 4; ++ni)
#pragma unroll
      for (int r = 0; r < 4; ++r) {
        const int row = m4 + (mi << 4) + (lk << 2) + r;
        const int col = c4 + (ni << 4) + lr;
        float v = acc4[mi][ni][r] + bv4[ni];
        out[((size_t)(row0 + row) << 9) + col] = fmaxf(v, 0.f);
      }
}

// ---------------- workspace layout (bytes) ----------------
#define OFF_W     0u          // w[B][18] f32        : 1179648
#define OFF_XB    1179648u    // xb[B][512] bf16     : 16777216
#define OFF_W1T   17956864u   // [18][256][512] bf16 : 4718592
#define OFF_W2T   22675456u   // [18][128][256] bf16 : 1179648
#define OFF_W3T   23855104u   // [18][128][128] bf16 : 589824
#define OFF_WAGGT 24444928u   // [512][640] bf16     : 655360
#define OFF_WAT   25100288u   // [18][512] f32       : 36864  (end 25137152)

extern "C" void kernel_launch(void* const* d_in, const int* in_sizes, int n_in,
                              void* d_out, int out_size, void* d_ws, size_t ws_size,
                              hipStream_t stream) {
  const float* X    = (const float*)d_in[0];
  const float* GV   = (const float*)d_in[1];
  const float* W1   = (const float*)d_in[2];
  const float* b1   = (const float*)d_in[3];
  const float* W2   = (const float*)d_in[4];
  const float* b2   = (const float*)d_in[5];
  const float* W3   = (const float*)d_in[6];
  const float* b3   = (const float*)d_in[7];
  const float* Wa   = (const float*)d_in[8];
  const float* ba   = (const float*)d_in[9];
  const float* Wagg = (const float*)d_in[10];
  const float* bagg = (const float*)d_in[11];
  float* out = (float*)d_out;
  char* ws = (char*)d_ws;

  float* w_ws           = (float*)(ws + OFF_W);
  unsigned short* xb    = (unsigned short*)(ws + OFF_XB);
  unsigned short* w1t   = (unsigned short*)(ws + OFF_W1T);
  unsigned short* w2t   = (unsigned short*)(ws + OFF_W2T);
  unsigned short* w3t   = (unsigned short*)(ws + OFF_W3T);
  unsigned short* waggt = (unsigned short*)(ws + OFF_WAGGT);
  float* wat            = (float*)(ws + OFF_WAT);

  k_transpose<<<dim3(32, 18), 256, 0, stream>>>(W1, w1t, 512, 256);
  k_transpose<<<dim3(8, 18), 256, 0, stream>>>(W2, w2t, 256, 128);
  k_transpose<<<dim3(4, 18), 256, 0, stream>>>(W3, w3t, 128, 128);
  k_transpose<<<dim3(80, 1), 256, 0, stream>>>(Wagg, waggt, 640, 512);
  k_wat<<<36, 256, 0, stream>>>(Wa, wat);
  k_attn<<<4096, 256, 0, stream>>>(X, GV, wat, ba, w_ws, xb);
  k_main<<<256, 1024, 0, stream>>>(xb, w_ws, w1t, w2t, w3t, waggt,
                                   b1, b2, b3, bagg, out);
}

// Round 3
// 334.852 us; speedup vs baseline: 1.6454x; 1.6454x over previous
//
#include <hip/hip_runtime.h>

#define NB 16384
#define ND 512
#define NH 128
#define NHH 256
#define NG 18

typedef short s8v __attribute__((ext_vector_type(8)));
typedef __bf16 bf8v __attribute__((ext_vector_type(8)));
typedef float f4v __attribute__((ext_vector_type(4)));
typedef unsigned int u4v __attribute__((ext_vector_type(4)));

static __device__ __forceinline__ unsigned short f2bf(float f) {
  unsigned int u = __builtin_bit_cast(unsigned int, f);
  u += 0x7FFFu + ((u >> 16) & 1u);
  return (unsigned short)(u >> 16);
}

static __device__ __forceinline__ f4v mfma16(s8v a, s8v b, f4v c) {
  return __builtin_amdgcn_mfma_f32_16x16x32_bf16(
      __builtin_bit_cast(bf8v, a), __builtin_bit_cast(bf8v, b), c, 0, 0, 0);
}

// ---- weight transpose+convert: out[g][c][r] = bf16(in[g][r][c]) ----
__global__ __launch_bounds__(256) void k_transpose(const float* __restrict__ in,
                                                   unsigned short* __restrict__ out,
                                                   int R, int C) {
  __shared__ float t[64][65];
  const int g = blockIdx.y;
  const int nCt = C >> 6;
  const int tr = blockIdx.x / nCt;
  const int tc = blockIdx.x - tr * nCt;
  const int lw = threadIdx.x >> 6;
  const int lc = threadIdx.x & 63;
  const float* ip = in + (size_t)g * R * C + (size_t)(tr << 6) * C + (tc << 6);
#pragma unroll
  for (int i = 0; i < 16; ++i) {
    int r = (i << 2) + lw;
    t[r][lc] = ip[(size_t)r * C + lc];
  }
  __syncthreads();
  unsigned short* op = out + (size_t)g * R * C + (size_t)(tc << 6) * R + (tr << 6);
#pragma unroll
  for (int i = 0; i < 16; ++i) {
    int r = (i << 2) + lw;
    op[(size_t)r * R + lc] = f2bf(t[lc][r]);
  }
}

// Wa [512][18] -> WaT [18][512] f32
__global__ __launch_bounds__(256) void k_wat(const float* __restrict__ wa,
                                             float* __restrict__ wat) {
  int tid = blockIdx.x * 256 + threadIdx.x;
  if (tid < NG * ND) {
    int g = tid >> 9, d = tid & (ND - 1);
    wat[tid] = wa[d * NG + g];
  }
}

// attention weights w[B,G] = softmax(X@Wa+ba)*gv, plus X -> bf16
__global__ __launch_bounds__(256) void k_attn(const float* __restrict__ X,
                                              const float* __restrict__ GV,
                                              const float* __restrict__ wat,
                                              const float* __restrict__ ba,
                                              float* __restrict__ w,
                                              unsigned short* __restrict__ xb) {
  __shared__ float wl[NG * ND];
  const int tid = threadIdx.x;
  for (int i = tid; i < NG * ND; i += 256) wl[i] = wat[i];
  __syncthreads();
  const int lane = tid & 63;
  const int row = (blockIdx.x << 2) + (tid >> 6);
  const float* xr = X + (size_t)row * ND + (lane << 3);
  float x[8];
  {
    float4 a = *(const float4*)xr;
    float4 b = *(const float4*)(xr + 4);
    x[0] = a.x; x[1] = a.y; x[2] = a.z; x[3] = a.w;
    x[4] = b.x; x[5] = b.y; x[6] = b.z; x[7] = b.w;
  }
  {
    u4v p;
#pragma unroll
    for (int j = 0; j < 4; ++j)
      p[j] = (unsigned)f2bf(x[2 * j]) | ((unsigned)f2bf(x[2 * j + 1]) << 16);
    *(u4v*)(xb + (size_t)row * ND + (lane << 3)) = p;
  }
  float lg[NG];
#pragma unroll
  for (int g = 0; g < NG; ++g) {
    const float* wr = wl + g * ND + (lane << 3);
    float s = 0.f;
#pragma unroll
    for (int j = 0; j < 8; ++j) s += x[j] * wr[j];
    lg[g] = s;
  }
#pragma unroll
  for (int off = 32; off > 0; off >>= 1) {
#pragma unroll
    for (int g = 0; g < NG; ++g) lg[g] += __shfl_xor(lg[g], off);
  }
  float m = -3.4e38f;
#pragma unroll
  for (int g = 0; g < NG; ++g) { lg[g] += ba[g]; m = fmaxf(m, lg[g]); }
  float s = 0.f;
#pragma unroll
  for (int g = 0; g < NG; ++g) { lg[g] = expf(lg[g] - m); s += lg[g]; }
  float inv = 1.f / s;
  if (lane < NG) {
    float gv = GV[(size_t)row * NG + lane];
    w[(size_t)row * NG + lane] = gv > 0.f ? lg[lane] * inv * gv : 0.f;
  }
}

// fused experts + aggregation. 1 block = 64 rows, 8 waves, deep pipelining.
__global__ __launch_bounds__(512, 2) void k_main(
    const unsigned short* __restrict__ xb,    // [B][512] bf16
    const float* __restrict__ wbg,            // [B][18]
    const unsigned short* __restrict__ w1t,   // [18][256][512] bf16
    const unsigned short* __restrict__ w2t,   // [18][128][256]
    const unsigned short* __restrict__ w3t,   // [18][128][128]
    const unsigned short* __restrict__ waggt, // [512][640]
    const float* __restrict__ b1, const float* __restrict__ b2,
    const float* __restrict__ b3, const float* __restrict__ bagg,
    float* __restrict__ out) {
  __shared__ __align__(16) char smem[119808];
  char* const XT = smem;                 // [64][512] bf16, stride 1024B, swz
  char* const H1 = smem + 65536;         // [64][256] bf16, stride 512B, swz
  char* const H2 = smem + 98304;         // [64][128] bf16, stride 256B, swz
  float* const WL = (float*)(smem + 114688); // [64][20]

  const int tid = threadIdx.x;
  const int row0 = blockIdx.x << 6;

#pragma unroll
  for (int i = 0; i < 8; ++i) {
    int idx = (i << 9) + tid;
    int r = idx >> 6, c16 = idx & 63;
    u4v v = *(const u4v*)(xb + ((size_t)(row0 + r) << 9) + (c16 << 3));
    int byte = (r << 10) + (c16 << 4);
    *(u4v*)(XT + (byte ^ ((r & 7) << 4))) = v;
  }
  for (int i = tid; i < 64 * NG; i += 512) {
    int r = i / NG, g = i - r * NG;
    WL[r * 20 + g] = wbg[(size_t)(row0 + r) * NG + g];
  }

  const int wid = tid >> 6, lane = tid & 63;
  const int lr = lane & 15, lk = lane >> 4;
  const int n1 = wid << 5;            // GEMM1 col base (8 waves x 32 = 256)
  const int mr0 = (wid >> 2) << 5;    // GEMM2/3 row base (0 or 32)
  const int nc0 = (wid & 3) << 5;     // GEMM2/3 col base
  const int n4 = wid << 6;            // GEMM4 col base

  // per-wave B pointers (genre 0)
  const unsigned short* const bp10 = w1t + ((size_t)(n1 + lr) << 9) + (lk << 3);
  const unsigned short* const bp11 = w1t + ((size_t)(n1 + 16 + lr) << 9) + (lk << 3);
  const unsigned short* const bp20 = w2t + ((size_t)(nc0 + lr) << 8) + (lk << 3);
  const unsigned short* const bp21 = w2t + ((size_t)(nc0 + 16 + lr) << 8) + (lk << 3);
  const unsigned short* const bp30 = w3t + ((size_t)(nc0 + lr) << 7) + (lk << 3);
  const unsigned short* const bp31 = w3t + ((size_t)(nc0 + 16 + lr) << 7) + (lk << 3);

  // prefetch GEMM1 g=0 ks=0 B-fragments (latency hides under staging barrier)
  s8v nx10 = *(const s8v*)bp10;
  s8v nx11 = *(const s8v*)bp11;
  s8v nx20, nx21, nx30, nx31;

  __syncthreads();

#define LDXT(row, ks) \
  (*(const s8v*)(XT + ((((row) << 10) + ((ks) << 6) + (lk << 4)) ^ (((row) & 7) << 4))))
#define LDH1(row, ks) \
  (*(const s8v*)(H1 + ((((row) << 9) + ((ks) << 6) + (lk << 4)) ^ (((row) & 7) << 4))))
#define LDH2(row, ks) \
  (*(const s8v*)(H2 + ((((row) << 8) + ((ks) << 6) + (lk << 4)) ^ (((row) & 7) << 4))))

  f4v racc[2][2];
#pragma unroll
  for (int i = 0; i < 2; ++i)
#pragma unroll
    for (int j = 0; j < 2; ++j) racc[i][j] = (f4v){0.f, 0.f, 0.f, 0.f};

  for (int g = 0; g < NG; ++g) {
    const size_t o1 = (size_t)g * (NHH * ND);
    const size_t o2 = (size_t)g * (NH * NHH);
    const size_t o3 = (size_t)g * (NH * NH);

    // ---------- GEMM1: h1 = relu(X @ W1[g] + b1[g])  [64,256] ----------
    const float bv1[2] = {b1[g * NHH + n1 + lr], b1[g * NHH + n1 + 16 + lr]};
    f4v acc1[4][2];
#pragma unroll
    for (int mi = 0; mi < 4; ++mi)
#pragma unroll
      for (int ni = 0; ni < 2; ++ni) acc1[mi][ni] = (f4v){0.f, 0.f, 0.f, 0.f};
    {
      s8v ac[4], bc0 = nx10, bc1 = nx11;
#pragma unroll
      for (int mi = 0; mi < 4; ++mi) ac[mi] = LDXT((mi << 4) + lr, 0);
#pragma unroll
      for (int ks = 0; ks < 16; ++ks) {
        s8v an[4], bn0, bn1;
        if (ks < 15) {
          bn0 = *(const s8v*)(bp10 + o1 + ((ks + 1) << 5));
          bn1 = *(const s8v*)(bp11 + o1 + ((ks + 1) << 5));
#pragma unroll
          for (int mi = 0; mi < 4; ++mi) an[mi] = LDXT((mi << 4) + lr, ks + 1);
        }
#pragma unroll
        for (int mi = 0; mi < 4; ++mi) {
          acc1[mi][0] = mfma16(ac[mi], bc0, acc1[mi][0]);
          acc1[mi][1] = mfma16(ac[mi], bc1, acc1[mi][1]);
        }
        if (ks < 15) {
#pragma unroll
          for (int mi = 0; mi < 4; ++mi) ac[mi] = an[mi];
          bc0 = bn0; bc1 = bn1;
        }
      }
    }
#pragma unroll
    for (int mi = 0; mi < 4; ++mi)
#pragma unroll
      for (int ni = 0; ni < 2; ++ni)
#pragma unroll
        for (int r = 0; r < 4; ++r) {
          const int row = (mi << 4) + (lk << 2) + r;
          const int col = n1 + (ni << 4) + lr;
          float v = fmaxf(acc1[mi][ni][r] + bv1[ni], 0.f);
          const int byte = (row << 9) + (col << 1);
          *(unsigned short*)(H1 + (byte ^ ((row & 7) << 4))) = f2bf(v);
        }
    // prefetch GEMM2 ks=0 B (drains during barrier)
    nx20 = *(const s8v*)(bp20 + o2);
    nx21 = *(const s8v*)(bp21 + o2);
    __syncthreads();

    // ---------- GEMM2: h2 = relu(h1 @ W2[g] + b2[g])  [64,128] ----------
    const float bv2[2] = {b2[g * NH + nc0 + lr], b2[g * NH + nc0 + 16 + lr]};
    f4v acc2[2][2];
#pragma unroll
    for (int mi = 0; mi < 2; ++mi)
#pragma unroll
      for (int ni = 0; ni < 2; ++ni) acc2[mi][ni] = (f4v){0.f, 0.f, 0.f, 0.f};
    {
      s8v ac[2], bc0 = nx20, bc1 = nx21;
#pragma unroll
      for (int mi = 0; mi < 2; ++mi) ac[mi] = LDH1(mr0 + (mi << 4) + lr, 0);
#pragma unroll
      for (int ks = 0; ks < 8; ++ks) {
        s8v an[2], bn0, bn1;
        if (ks < 7) {
          bn0 = *(const s8v*)(bp20 + o2 + ((ks + 1) << 5));
          bn1 = *(const s8v*)(bp21 + o2 + ((ks + 1) << 5));
#pragma unroll
          for (int mi = 0; mi < 2; ++mi) an[mi] = LDH1(mr0 + (mi << 4) + lr, ks + 1);
        }
#pragma unroll
        for (int mi = 0; mi < 2; ++mi) {
          acc2[mi][0] = mfma16(ac[mi], bc0, acc2[mi][0]);
          acc2[mi][1] = mfma16(ac[mi], bc1, acc2[mi][1]);
        }
        if (ks < 7) {
          ac[0] = an[0]; ac[1] = an[1];
          bc0 = bn0; bc1 = bn1;
        }
      }
    }
#pragma unroll
    for (int mi = 0; mi < 2; ++mi)
#pragma unroll
      for (int ni = 0; ni < 2; ++ni)
#pragma unroll
        for (int r = 0; r < 4; ++r) {
          const int row = mr0 + (mi << 4) + (lk << 2) + r;
          const int col = nc0 + (ni << 4) + lr;
          float v = fmaxf(acc2[mi][ni][r] + bv2[ni], 0.f);
          const int byte = (row << 8) + (col << 1);
          *(unsigned short*)(H2 + (byte ^ ((row & 7) << 4))) = f2bf(v);
        }
    // prefetch GEMM3 ks=0 B
    nx30 = *(const s8v*)(bp30 + o3);
    nx31 = *(const s8v*)(bp31 + o3);
    __syncthreads();

    // ---------- GEMM3: h3 = h2 @ W3[g] + b3[g]; racc += w*h3 ----------
    const float bv3[2] = {b3[g * NH + nc0 + lr], b3[g * NH + nc0 + 16 + lr]};
    f4v acc3[2][2];
#pragma unroll
    for (int mi = 0; mi < 2; ++mi)
#pragma unroll
      for (int ni = 0; ni < 2; ++ni) acc3[mi][ni] = (f4v){0.f, 0.f, 0.f, 0.f};
    {
      s8v ac[2], bc0 = nx30, bc1 = nx31;
#pragma unroll
      for (int mi = 0; mi < 2; ++mi) ac[mi] = LDH2(mr0 + (mi << 4) + lr, 0);
#pragma unroll
      for (int ks = 0; ks < 4; ++ks) {
        s8v an[2], bn0, bn1;
        if (ks < 3) {
          bn0 = *(const s8v*)(bp30 + o3 + ((ks + 1) << 5));
          bn1 = *(const s8v*)(bp31 + o3 + ((ks + 1) << 5));
#pragma unroll
          for (int mi = 0; mi < 2; ++mi) an[mi] = LDH2(mr0 + (mi << 4) + lr, ks + 1);
        }
#pragma unroll
        for (int mi = 0; mi < 2; ++mi) {
          acc3[mi][0] = mfma16(ac[mi], bc0, acc3[mi][0]);
          acc3[mi][1] = mfma16(ac[mi], bc1, acc3[mi][1]);
        }
        if (ks < 3) {
          ac[0] = an[0]; ac[1] = an[1];
          bc0 = bn0; bc1 = bn1;
        }
      }
    }
    // prefetch next genre's GEMM1 ks=0 B (no barrier between GEMM3 and GEMM1)
    if (g + 1 < NG) {
      const size_t o1n = (size_t)(g + 1) * (NHH * ND);
      nx10 = *(const s8v*)(bp10 + o1n);
      nx11 = *(const s8v*)(bp11 + o1n);
    }
#pragma unroll
    for (int mi = 0; mi < 2; ++mi)
#pragma unroll
      for (int ni = 0; ni < 2; ++ni)
#pragma unroll
        for (int r = 0; r < 4; ++r) {
          const int row = mr0 + (mi << 4) + (lk << 2) + r;
          const float wv = WL[row * 20 + g];
          racc[mi][ni][r] += wv * (acc3[mi][ni][r] + bv3[ni]);
        }
  }

  // ---------- GEMM4: out = relu([X | ref] @ Wagg + bagg)  [64,512] ----------
  const unsigned short* bp4[4];
#pragma unroll
  for (int ni = 0; ni < 4; ++ni)
    bp4[ni] = waggt + (size_t)(n4 + (ni << 4) + lr) * 640 + (lk << 3);
  // prefetch GEMM4 ks=0 B before the barriers
  s8v g4b[4];
#pragma unroll
  for (int ni = 0; ni < 4; ++ni) g4b[ni] = *(const s8v*)bp4[ni];

  __syncthreads();  // all GEMM3 H2 reads done before overwrite with ref
#pragma unroll
  for (int mi = 0; mi < 2; ++mi)
#pragma unroll
    for (int ni = 0; ni < 2; ++ni)
#pragma unroll
      for (int r = 0; r < 4; ++r) {
        const int row = mr0 + (mi << 4) + (lk << 2) + r;
        const int col = nc0 + (ni << 4) + lr;
        const int byte = (row << 8) + (col << 1);
        *(unsigned short*)(H2 + (byte ^ ((row & 7) << 4))) = f2bf(racc[mi][ni][r]);
      }
  __syncthreads();

  float bv4[4];
#pragma unroll
  for (int ni = 0; ni < 4; ++ni) bv4[ni] = bagg[n4 + (ni << 4) + lr];
  f4v acc4[4][4];
#pragma unroll
  for (int mi = 0; mi < 4; ++mi)
#pragma unroll
    for (int ni = 0; ni < 4; ++ni) acc4[mi][ni] = (f4v){0.f, 0.f, 0.f, 0.f};
  {
    s8v ac[4], bc[4];
#pragma unroll
    for (int ni = 0; ni < 4; ++ni) bc[ni] = g4b[ni];
#pragma unroll
    for (int mi = 0; mi < 4; ++mi) ac[mi] = LDXT((mi << 4) + lr, 0);
#pragma unroll
    for (int ks = 0; ks < 20; ++ks) {
      s8v an[4], bn[4];
      if (ks < 19) {
        const int kn = ks + 1;
#pragma unroll
        for (int ni = 0; ni < 4; ++ni)
          bn[ni] = *(const s8v*)(bp4[ni] + (kn << 5));
        if (kn < 16) {
#pragma unroll
          for (int mi = 0; mi < 4; ++mi) an[mi] = LDXT((mi << 4) + lr, kn);
        } else {
#pragma unroll
          for (int mi = 0; mi < 4; ++mi) an[mi] = LDH2((mi << 4) + lr, kn - 16);
        }
      }
#pragma unroll
      for (int mi = 0; mi < 4; ++mi)
#pragma unroll
        for (int ni = 0; ni < 4; ++ni)
          acc4[mi][ni] = mfma16(ac[mi], bc[ni], acc4[mi][ni]);
      if (ks < 19) {
#pragma unroll
        for (int mi = 0; mi < 4; ++mi) ac[mi] = an[mi];
#pragma unroll
        for (int ni = 0; ni < 4; ++ni) bc[ni] = bn[ni];
      }
    }
  }
#pragma unroll
  for (int mi = 0; mi < 4; ++mi)
#pragma unroll
    for (int ni = 0; ni < 4; ++ni)
#pragma unroll
      for (int r = 0; r < 4; ++r) {
        const int row = (mi << 4) + (lk << 2) + r;
        const int col = n4 + (ni << 4) + lr;
        float v = acc4[mi][ni][r] + bv4[ni];
        out[((size_t)(row0 + row) << 9) + col] = fmaxf(v, 0.f);
      }
#undef LDXT
#undef LDH1
#undef LDH2
}

// ---------------- workspace layout (bytes) ----------------
#define OFF_W     0u          // w[B][18] f32        : 1179648
#define OFF_XB    1179648u    // xb[B][512] bf16     : 16777216
#define OFF_W1T   17956864u   // [18][256][512] bf16 : 4718592
#define OFF_W2T   22675456u   // [18][128][256] bf16 : 1179648
#define OFF_W3T   23855104u   // [18][128][128] bf16 : 589824
#define OFF_WAGGT 24444928u   // [512][640] bf16     : 655360
#define OFF_WAT   25100288u   // [18][512] f32       : 36864  (end 25137152)

extern "C" void kernel_launch(void* const* d_in, const int* in_sizes, int n_in,
                              void* d_out, int out_size, void* d_ws, size_t ws_size,
                              hipStream_t stream) {
  const float* X    = (const float*)d_in[0];
  const float* GV   = (const float*)d_in[1];
  const float* W1   = (const float*)d_in[2];
  const float* b1   = (const float*)d_in[3];
  const float* W2   = (const float*)d_in[4];
  const float* b2   = (const float*)d_in[5];
  const float* W3   = (const float*)d_in[6];
  const float* b3   = (const float*)d_in[7];
  const float* Wa   = (const float*)d_in[8];
  const float* ba   = (const float*)d_in[9];
  const float* Wagg = (const float*)d_in[10];
  const float* bagg = (const float*)d_in[11];
  float* out = (float*)d_out;
  char* ws = (char*)d_ws;

  float* w_ws           = (float*)(ws + OFF_W);
  unsigned short* xb    = (unsigned short*)(ws + OFF_XB);
  unsigned short* w1t   = (unsigned short*)(ws + OFF_W1T);
  unsigned short* w2t   = (unsigned short*)(ws + OFF_W2T);
  unsigned short* w3t   = (unsigned short*)(ws + OFF_W3T);
  unsigned short* waggt = (unsigned short*)(ws + OFF_WAGGT);
  float* wat            = (float*)(ws + OFF_WAT);

  k_transpose<<<dim3(32, 18), 256, 0, stream>>>(W1, w1t, 512, 256);
  k_transpose<<<dim3(8, 18), 256, 0, stream>>>(W2, w2t, 256, 128);
  k_transpose<<<dim3(4, 18), 256, 0, stream>>>(W3, w3t, 128, 128);
  k_transpose<<<dim3(80, 1), 256, 0, stream>>>(Wagg, waggt, 640, 512);
  k_wat<<<36, 256, 0, stream>>>(Wa, wat);
  k_attn<<<4096, 256, 0, stream>>>(X, GV, wat, ba, w_ws, xb);
  k_main<<<256, 512, 0, stream>>>(xb, w_ws, w1t, w2t, w3t, waggt,
                                  b1, b2, b3, bagg, out);
}